// Round 1
// baseline (959.895 us; speedup 1.0000x reference)
//
#include <hip/hip_runtime.h>
#include <math.h>

#define NB    64        // graphs
#define NPER  1024      // nodes per graph
#define NTOT  65536     // total nodes
#define ETOT  1048576   // edges
#define FEAT  64
#define HID   128
#define KSEL  10
#define MAXDEG 64       // CSR slot capacity per node (max in-degree ~40)

// ---------------- CSR build ----------------
__global__ __launch_bounds__(256) void csr_k(const int* __restrict__ src,
                                             const int* __restrict__ dst,
                                             int* __restrict__ cnt,
                                             int* __restrict__ col) {
    int e = blockIdx.x * 256 + threadIdx.x;
    if (e >= ETOT) return;
    int d = dst[e];
    int s = src[e];
    int pos = atomicAdd(&cnt[d], 1);
    col[(size_t)d * MAXDEG + pos] = s;
}

__global__ __launch_bounds__(256) void dinv_k(const int* __restrict__ cnt,
                                              float* __restrict__ dinv) {
    int v = blockIdx.x * 256 + threadIdx.x;
    if (v >= NTOT) return;
    dinv[v] = rsqrtf((float)cnt[v] + 1.0f);
}

// ---------------- fp32 GEMM: Y[N x 128] = A[N x K] @ W[K x 128] (+ per-graph row gproj) ---
// block = 256 threads, tile 64 rows x 128 cols, K-tile 32.
__global__ __launch_bounds__(256) void gemm_k(const float* __restrict__ A,
                                              const float* __restrict__ W,
                                              float* __restrict__ Y,
                                              const float* __restrict__ gproj,
                                              int K) {
    __shared__ float At[32][68];    // transposed A tile, stride 68 keeps 16B align (272B rows)
    __shared__ float Wt[32][128];
    int t = threadIdx.x;
    int row0 = blockIdx.x * 64;
    int tx = t & 31;    // col group: c = tx*4
    int ty = t >> 5;    // row group: r = ty*8

    float acc[8][4];
#pragma unroll
    for (int i = 0; i < 8; ++i)
#pragma unroll
        for (int j = 0; j < 4; ++j) acc[i][j] = 0.f;

    for (int kt = 0; kt < K; kt += 32) {
        // stage A tile (64 rows x 32 k), transposed
        {
            int r = t >> 5;      // 0..7
            int k = t & 31;
#pragma unroll
            for (int rr = 0; rr < 8; ++rr) {
                At[k][r + rr * 8] = A[(size_t)(row0 + r + rr * 8) * K + kt + k];
            }
        }
        // stage W tile (32 k x 128 cols)
        {
            int c = t & 127;
            int kr = t >> 7;     // 0..1
#pragma unroll
            for (int kk = 0; kk < 16; ++kk) {
                Wt[kr + kk * 2][c] = W[(size_t)(kt + kr + kk * 2) * 128 + c];
            }
        }
        __syncthreads();
#pragma unroll
        for (int k = 0; k < 32; ++k) {
            float4 a0 = *(const float4*)&At[k][ty * 8];
            float4 a1 = *(const float4*)&At[k][ty * 8 + 4];
            float4 w  = *(const float4*)&Wt[k][tx * 4];
            float a[8] = {a0.x, a0.y, a0.z, a0.w, a1.x, a1.y, a1.z, a1.w};
#pragma unroll
            for (int i = 0; i < 8; ++i) {
                acc[i][0] += a[i] * w.x;
                acc[i][1] += a[i] * w.y;
                acc[i][2] += a[i] * w.z;
                acc[i][3] += a[i] * w.w;
            }
        }
        __syncthreads();
    }

    float4 g4 = make_float4(0.f, 0.f, 0.f, 0.f);
    if (gproj) {
        int g = row0 >> 10;   // 64-row tile never crosses a 1024-node graph
        g4 = *(const float4*)&gproj[(size_t)g * 128 + tx * 4];
    }
#pragma unroll
    for (int i = 0; i < 8; ++i) {
        int r = row0 + ty * 8 + i;
        float4 o;
        o.x = acc[i][0] + g4.x;
        o.y = acc[i][1] + g4.y;
        o.z = acc[i][2] + g4.z;
        o.w = acc[i][3] + g4.w;
        *(float4*)&Y[(size_t)r * 128 + tx * 4] = o;
    }
}

// ---------------- GCN aggregation (gather form), 2 nodes per 256-thread block --------
__global__ __launch_bounds__(256) void agg_k(const float* __restrict__ Y,
                                             const int* __restrict__ col,
                                             const int* __restrict__ cnt,
                                             const float* __restrict__ dinv,
                                             const float* __restrict__ bias,
                                             float* __restrict__ out,
                                             int relu) {
    int t = threadIdx.x;
    int v = blockIdx.x * 2 + (t >> 7);
    int f = t & 127;
    float dv = dinv[v];
    float acc = Y[(size_t)v * 128 + f] * dv * dv;   // self-loop
    int n = cnt[v];
    const int* cp = col + (size_t)v * MAXDEG;
    for (int i = 0; i < n; ++i) {
        int s = cp[i];
        float w = dinv[s] * dv;
        acc += Y[(size_t)s * 128 + f] * w;
    }
    acc += bias[f];
    if (relu) acc = fmaxf(acc, 0.f);
    out[(size_t)v * 128 + f] = acc;
}

// ---------------- per-graph max pool (partials: 8 chunks per graph) -------------------
__global__ __launch_bounds__(128) void maxpool_k(const float* __restrict__ h0,
                                                 float* __restrict__ part) {
    int b = blockIdx.x;          // 0..511 ; rows b*128 .. b*128+127
    int f = threadIdx.x;
    const float* p = h0 + (size_t)b * 128 * 128 + f;
    float m = -INFINITY;
    for (int i = 0; i < 128; ++i) m = fmaxf(m, p[(size_t)i * 128]);
    part[(size_t)b * 128 + f] = m;
}

// ---------------- glob = maxpool@Wf + bf ; gproj = glob @ W2[128:256,:] --------------
__global__ __launch_bounds__(128) void glob_k(const float* __restrict__ part,
                                              const float* __restrict__ Wf,
                                              const float* __restrict__ bf,
                                              const float* __restrict__ W2,
                                              float* __restrict__ gproj) {
    __shared__ float mp[128];
    __shared__ float gl[128];
    int g = blockIdx.x, t = threadIdx.x;
    float m = -INFINITY;
    for (int c = 0; c < 8; ++c)
        m = fmaxf(m, part[((size_t)g * 8 + c) * 128 + t]);
    mp[t] = m;
    __syncthreads();
    float acc = bf[t];
    for (int k = 0; k < 128; ++k) acc += mp[k] * Wf[(size_t)k * 128 + t];
    gl[t] = acc;
    __syncthreads();
    float acc2 = 0.f;
    for (int k = 0; k < 128; ++k) acc2 += gl[k] * W2[(size_t)(128 + k) * 128 + t];
    gproj[(size_t)g * 128 + t] = acc2;
}

// ---------------- lin3[v] = dot(h[v,:], W3) : one wave per node ----------------------
__global__ __launch_bounds__(256) void lin3_k(const float* __restrict__ h,
                                              const float* __restrict__ W3,
                                              float* __restrict__ lin3) {
    int t = threadIdx.x;
    int v = blockIdx.x * 4 + (t >> 6);
    int l = t & 63;
    float a = h[(size_t)v * 128 + l] * W3[l] + h[(size_t)v * 128 + 64 + l] * W3[64 + l];
#pragma unroll
    for (int off = 32; off > 0; off >>= 1) a += __shfl_down(a, off, 64);
    if (l == 0) lin3[v] = a;
}

// ---------------- scalar aggregation for logits --------------------------------------
__global__ __launch_bounds__(256) void sagg_k(const float* __restrict__ lin3,
                                              const int* __restrict__ col,
                                              const int* __restrict__ cnt,
                                              const float* __restrict__ dinv,
                                              const float* __restrict__ b3,
                                              float* __restrict__ logits) {
    int v = blockIdx.x * 256 + threadIdx.x;
    if (v >= NTOT) return;
    float dv = dinv[v];
    float acc = lin3[v] * dv;       // self term (will be *dv again below)
    int n = cnt[v];
    const int* cp = col + (size_t)v * MAXDEG;
    for (int i = 0; i < n; ++i) {
        int s = cp[i];
        acc += lin3[s] * dinv[s];
    }
    logits[v] = acc * dv + b3[0];
}

// ---------------- per-graph top-K threshold + mask -----------------------------------
__global__ __launch_bounds__(256) void mask_k(const float* __restrict__ logits,
                                              float* __restrict__ out) {
    __shared__ float sl[1024];
    __shared__ float rv[256];
    __shared__ int   ri[256];
    __shared__ float sth;
    int g = blockIdx.x, t = threadIdx.x;
    const float* lg = logits + (size_t)g * 1024;
#pragma unroll
    for (int i = 0; i < 4; ++i) sl[t + 256 * i] = lg[t + 256 * i];
    __syncthreads();
    for (int pass = 0; pass < KSEL; ++pass) {
        float bv = -INFINITY;
        int bi = 0;
#pragma unroll
        for (int i = 0; i < 4; ++i) {
            float v = sl[t + 256 * i];
            if (v > bv) { bv = v; bi = t + 256 * i; }
        }
        rv[t] = bv; ri[t] = bi;
        __syncthreads();
        for (int s = 128; s > 0; s >>= 1) {
            if (t < s) {
                if (rv[t + s] > rv[t]) { rv[t] = rv[t + s]; ri[t] = ri[t + s]; }
            }
            __syncthreads();
        }
        if (t == 0) { sth = rv[0]; sl[ri[0]] = -INFINITY; }
        __syncthreads();
    }
    float th = sth;
#pragma unroll
    for (int i = 0; i < 4; ++i) {
        float v = lg[t + 256 * i];
        out[(size_t)g * 1024 + t + 256 * i] = (v >= th) ? 1.f : 0.f;
    }
}

// =====================================================================================
extern "C" void kernel_launch(void* const* d_in, const int* in_sizes, int n_in,
                              void* d_out, int out_size, void* d_ws, size_t ws_size,
                              hipStream_t stream) {
    const float* x        = (const float*)d_in[0];
    const int*   edge_src = (const int*)d_in[1];
    const int*   edge_dst = (const int*)d_in[2];
    // d_in[3] = uniforms : unused in eval path
    const float* W0 = (const float*)d_in[4];
    const float* b0 = (const float*)d_in[5];
    const float* W1 = (const float*)d_in[6];
    const float* b1 = (const float*)d_in[7];
    const float* Wf = (const float*)d_in[8];
    const float* bf = (const float*)d_in[9];
    const float* W2 = (const float*)d_in[10];
    const float* b2 = (const float*)d_in[11];
    const float* W3 = (const float*)d_in[12];
    const float* b3 = (const float*)d_in[13];
    float* out = (float*)d_out;

    // workspace carve-up (all re-initialized every launch)
    char* w = (char*)d_ws;
    int*   cnt    = (int*)w;   w += (size_t)NTOT * 4;
    float* dinv   = (float*)w; w += (size_t)NTOT * 4;
    int*   col    = (int*)w;   w += (size_t)NTOT * MAXDEG * 4;
    float* Y      = (float*)w; w += (size_t)NTOT * 128 * 4;
    float* h0     = (float*)w; w += (size_t)NTOT * 128 * 4;
    float* hA     = (float*)w; w += (size_t)NTOT * 128 * 4;
    float* part   = (float*)w; w += (size_t)512 * 128 * 4;
    float* gproj  = (float*)w; w += (size_t)NB * 128 * 4;
    float* lin3   = (float*)w; w += (size_t)NTOT * 4;
    float* logits = (float*)w; w += (size_t)NTOT * 4;

    hipMemsetAsync(cnt, 0, (size_t)NTOT * 4, stream);
    csr_k<<<ETOT / 256, 256, 0, stream>>>(edge_src, edge_dst, cnt, col);
    dinv_k<<<NTOT / 256, 256, 0, stream>>>(cnt, dinv);

    // conv0: h0 = relu(agg(x@W0) + b0)
    gemm_k<<<NTOT / 64, 256, 0, stream>>>(x, W0, Y, nullptr, FEAT);
    agg_k<<<NTOT / 2, 256, 0, stream>>>(Y, col, cnt, dinv, b0, h0, 1);

    // global: maxpool -> glob = mp@Wf+bf -> gproj = glob@W2[128:,:]
    maxpool_k<<<512, 128, 0, stream>>>(h0, part);
    glob_k<<<NB, 128, 0, stream>>>(part, Wf, bf, W2, gproj);

    // conv1 applied twice (same weights)
    gemm_k<<<NTOT / 64, 256, 0, stream>>>(h0, W1, Y, nullptr, HID);
    agg_k<<<NTOT / 2, 256, 0, stream>>>(Y, col, cnt, dinv, b1, hA, 1);
    gemm_k<<<NTOT / 64, 256, 0, stream>>>(hA, W1, Y, nullptr, HID);
    agg_k<<<NTOT / 2, 256, 0, stream>>>(Y, col, cnt, dinv, b1, hA, 1);

    // conv2 on concat: lin = hA@W2[:128,:] + gproj[graph], then agg
    gemm_k<<<NTOT / 64, 256, 0, stream>>>(hA, W2, Y, gproj, HID);
    agg_k<<<NTOT / 2, 256, 0, stream>>>(Y, col, cnt, dinv, b2, hA, 1);

    // logits = agg_scalar(hA @ W3) + b3
    lin3_k<<<NTOT / 4, 256, 0, stream>>>(hA, W3, lin3);
    sagg_k<<<NTOT / 256, 256, 0, stream>>>(lin3, col, cnt, dinv, b3, logits);

    // per-graph top-10 threshold mask
    mask_k<<<NB, 256, 0, stream>>>(logits, out);
}

// Round 2
// 418.245 us; speedup vs baseline: 2.2951x; 2.2951x over previous
//
#include <hip/hip_runtime.h>
#include <math.h>

#define NB    64        // graphs
#define NPER  1024      // nodes per graph
#define NTOT  65536     // total nodes
#define ETOT  1048576   // edges
#define FEAT  64
#define HID   128
#define KSEL  10
#define MAXDEG 64       // CSR slot capacity per node (max in-degree ~40)
#define NCH   8         // feature chunks of 16

// ---------------- CSR build ----------------
__global__ __launch_bounds__(256) void csr_k(const int* __restrict__ src,
                                             const int* __restrict__ dst,
                                             int* __restrict__ cnt,
                                             int* __restrict__ col) {
    int e = blockIdx.x * 256 + threadIdx.x;
    if (e >= ETOT) return;
    int d = dst[e];
    int s = src[e];
    int pos = atomicAdd(&cnt[d], 1);
    col[(size_t)d * MAXDEG + pos] = s;
}

__global__ __launch_bounds__(256) void dinv_k(const int* __restrict__ cnt,
                                              float* __restrict__ dinv) {
    int v = blockIdx.x * 256 + threadIdx.x;
    if (v >= NTOT) return;
    dinv[v] = rsqrtf((float)cnt[v] + 1.0f);
}

// pack (src, norm weight) per CSR slot: one 8B load per neighbor in the hot aggs
__global__ __launch_bounds__(256) void wgt_k(const int* __restrict__ col,
                                             const int* __restrict__ cnt,
                                             const float* __restrict__ dinv,
                                             int2* __restrict__ iw) {
    int idx = blockIdx.x * 256 + threadIdx.x;   // over NTOT*MAXDEG
    int v = idx >> 6, i = idx & 63;
    if (i >= cnt[v]) return;
    int s = col[idx];
    float w = dinv[s] * dinv[v];
    iw[idx] = make_int2(s, __float_as_int(w));
}

// ---------------- fp32 GEMM: Y[N x 128] = A[N x K] @ W[K x 128] (+ per-graph row gproj) ---
__global__ __launch_bounds__(256) void gemm_k(const float* __restrict__ A,
                                              const float* __restrict__ W,
                                              float* __restrict__ Y,
                                              const float* __restrict__ gproj,
                                              int K) {
    __shared__ float At[32][68];
    __shared__ float Wt[32][128];
    int t = threadIdx.x;
    int row0 = blockIdx.x * 64;
    int tx = t & 31;
    int ty = t >> 5;

    float acc[8][4];
#pragma unroll
    for (int i = 0; i < 8; ++i)
#pragma unroll
        for (int j = 0; j < 4; ++j) acc[i][j] = 0.f;

    for (int kt = 0; kt < K; kt += 32) {
        {
            int r = t >> 5;
            int k = t & 31;
#pragma unroll
            for (int rr = 0; rr < 8; ++rr)
                At[k][r + rr * 8] = A[(size_t)(row0 + r + rr * 8) * K + kt + k];
        }
        {
            int c = t & 127;
            int kr = t >> 7;
#pragma unroll
            for (int kk = 0; kk < 16; ++kk)
                Wt[kr + kk * 2][c] = W[(size_t)(kt + kr + kk * 2) * 128 + c];
        }
        __syncthreads();
#pragma unroll
        for (int k = 0; k < 32; ++k) {
            float4 a0 = *(const float4*)&At[k][ty * 8];
            float4 a1 = *(const float4*)&At[k][ty * 8 + 4];
            float4 w  = *(const float4*)&Wt[k][tx * 4];
            float a[8] = {a0.x, a0.y, a0.z, a0.w, a1.x, a1.y, a1.z, a1.w};
#pragma unroll
            for (int i = 0; i < 8; ++i) {
                acc[i][0] += a[i] * w.x;
                acc[i][1] += a[i] * w.y;
                acc[i][2] += a[i] * w.z;
                acc[i][3] += a[i] * w.w;
            }
        }
        __syncthreads();
    }

    float4 g4 = make_float4(0.f, 0.f, 0.f, 0.f);
    if (gproj) {
        int g = row0 >> 10;
        g4 = *(const float4*)&gproj[(size_t)g * 128 + tx * 4];
    }
#pragma unroll
    for (int i = 0; i < 8; ++i) {
        int r = row0 + ty * 8 + i;
        float4 o;
        o.x = acc[i][0] + g4.x;
        o.y = acc[i][1] + g4.y;
        o.z = acc[i][2] + g4.z;
        o.w = acc[i][3] + g4.w;
        *(float4*)&Y[(size_t)r * 128 + tx * 4] = o;
    }
}

// ---------------- LDS-staged GCN aggregation --------------------------------------
// block = (graph g, feature chunk c of 16 floats); 1024 threads, 4 lanes per node.
// Stages the graph's Y column-chunk (1024 x 16 = 64 KB) into LDS, gathers from LDS.
// Optional fusions: per-graph feature max (part != null), lin3 partial dot (w3 != null).
// In-place safe: block writes exactly the columns it staged.
__global__ __launch_bounds__(1024) void agg_k(const float* __restrict__ Y,
                                              const int2* __restrict__ iw,
                                              const int* __restrict__ cnt,
                                              const float* __restrict__ dinv,
                                              const float* __restrict__ bias,
                                              float* __restrict__ out,
                                              float* __restrict__ lin3p,
                                              const float* __restrict__ W3,
                                              float* __restrict__ part) {
    __shared__ float4 sy4[4096];   // 64 KB
    int t = threadIdx.x;
    int g = blockIdx.x >> 3;
    int c = blockIdx.x & 7;
    int gbase = g << 10;

    const float* Yg = Y + (size_t)gbase * 128 + c * 16;
#pragma unroll
    for (int j = 0; j < 4; ++j) {
        int fl = j * 1024 + t;             // 0..4095
        int v = fl >> 2, fi = fl & 3;
        sy4[fl] = *(const float4*)(Yg + (size_t)v * 128 + fi * 4);
    }
    __syncthreads();

    int f4 = t & 3;
    int vl = t >> 2;                        // 0..255
    float4 bias4 = *(const float4*)(bias + c * 16 + f4 * 4);
    float4 w34 = make_float4(0.f, 0.f, 0.f, 0.f);
    if (W3) w34 = *(const float4*)(W3 + c * 16 + f4 * 4);
    float4 vmax = make_float4(-INFINITY, -INFINITY, -INFINITY, -INFINITY);

#pragma unroll 1
    for (int pass = 0; pass < 4; ++pass) {
        int v = pass * 256 + vl;
        int gv = gbase + v;
        float dv = dinv[gv];
        int n = cnt[gv];
        const int2* ip = iw + (size_t)gv * MAXDEG;
        float4 s4 = sy4[v * 4 + f4];
        float dvv = dv * dv;
        float4 acc;
        acc.x = s4.x * dvv; acc.y = s4.y * dvv; acc.z = s4.z * dvv; acc.w = s4.w * dvv;
        int i = 0;
        for (; i + 2 <= n; i += 2) {
            int2 e0 = ip[i], e1 = ip[i + 1];
            float w0 = __int_as_float(e0.y), w1 = __int_as_float(e1.y);
            float4 y0 = sy4[(e0.x - gbase) * 4 + f4];
            float4 y1 = sy4[(e1.x - gbase) * 4 + f4];
            acc.x += y0.x * w0 + y1.x * w1;
            acc.y += y0.y * w0 + y1.y * w1;
            acc.z += y0.z * w0 + y1.z * w1;
            acc.w += y0.w * w0 + y1.w * w1;
        }
        if (i < n) {
            int2 e = ip[i];
            float w = __int_as_float(e.y);
            float4 y = sy4[(e.x - gbase) * 4 + f4];
            acc.x += y.x * w; acc.y += y.y * w; acc.z += y.z * w; acc.w += y.w * w;
        }
        acc.x = fmaxf(acc.x + bias4.x, 0.f);
        acc.y = fmaxf(acc.y + bias4.y, 0.f);
        acc.z = fmaxf(acc.z + bias4.z, 0.f);
        acc.w = fmaxf(acc.w + bias4.w, 0.f);
        if (out) *(float4*)(out + (size_t)gv * 128 + c * 16 + f4 * 4) = acc;
        if (W3) {
            float p = acc.x * w34.x + acc.y * w34.y + acc.z * w34.z + acc.w * w34.w;
            p += __shfl_xor(p, 1);
            p += __shfl_xor(p, 2);
            if (f4 == 0) lin3p[(size_t)c * NTOT + gv] = p;
        }
        if (part) {
            vmax.x = fmaxf(vmax.x, acc.x);
            vmax.y = fmaxf(vmax.y, acc.y);
            vmax.z = fmaxf(vmax.z, acc.z);
            vmax.w = fmaxf(vmax.w, acc.w);
        }
    }

    if (part) {   // tree-reduce max over 256 node groups, reusing sy4
        __syncthreads();
        sy4[t] = vmax;
        __syncthreads();
        for (int s = 128; s >= 1; s >>= 1) {
            if (vl < s) {
                float4 a = sy4[t], b = sy4[t + s * 4];
                a.x = fmaxf(a.x, b.x); a.y = fmaxf(a.y, b.y);
                a.z = fmaxf(a.z, b.z); a.w = fmaxf(a.w, b.w);
                sy4[t] = a;
            }
            __syncthreads();
        }
        if (t < 4) *(float4*)(part + (size_t)g * 128 + c * 16 + t * 4) = sy4[t];
    }
}

// ---------------- glob = maxpool@Wf + bf ; gproj = glob @ W2[128:256,:] --------------
__global__ __launch_bounds__(128) void glob_k(const float* __restrict__ part,
                                              const float* __restrict__ Wf,
                                              const float* __restrict__ bf,
                                              const float* __restrict__ W2,
                                              float* __restrict__ gproj) {
    __shared__ float mp[128];
    __shared__ float gl[128];
    int g = blockIdx.x, t = threadIdx.x;
    mp[t] = part[(size_t)g * 128 + t];
    __syncthreads();
    float acc = bf[t];
    for (int k = 0; k < 128; ++k) acc += mp[k] * Wf[(size_t)k * 128 + t];
    gl[t] = acc;
    __syncthreads();
    float acc2 = 0.f;
    for (int k = 0; k < 128; ++k) acc2 += gl[k] * W2[(size_t)(128 + k) * 128 + t];
    gproj[(size_t)g * 128 + t] = acc2;
}

// ---------------- lin3[v] = sum of 8 chunk partials ----------------------------------
__global__ __launch_bounds__(256) void lin3sum_k(const float* __restrict__ lin3p,
                                                 float* __restrict__ lin3) {
    int v = blockIdx.x * 256 + threadIdx.x;
    float s = 0.f;
#pragma unroll
    for (int c = 0; c < NCH; ++c) s += lin3p[(size_t)c * NTOT + v];
    lin3[v] = s;
}

// ---------------- scalar aggregation for logits --------------------------------------
__global__ __launch_bounds__(256) void sagg_k(const float* __restrict__ lin3,
                                              const int2* __restrict__ iw,
                                              const int* __restrict__ cnt,
                                              const float* __restrict__ dinv,
                                              const float* __restrict__ b3,
                                              float* __restrict__ logits) {
    int v = blockIdx.x * 256 + threadIdx.x;
    if (v >= NTOT) return;
    float dv = dinv[v];
    float acc = lin3[v] * dv * dv;
    int n = cnt[v];
    const int2* ip = iw + (size_t)v * MAXDEG;
    for (int i = 0; i < n; ++i) {
        int2 e = ip[i];
        acc += lin3[e.x] * __int_as_float(e.y);
    }
    logits[v] = acc + b3[0];
}

// ---------------- per-graph top-K threshold + mask -----------------------------------
__global__ __launch_bounds__(256) void mask_k(const float* __restrict__ logits,
                                              float* __restrict__ out) {
    __shared__ float sl[1024];
    __shared__ float rv[256];
    __shared__ int   ri[256];
    __shared__ float sth;
    int g = blockIdx.x, t = threadIdx.x;
    const float* lg = logits + (size_t)g * 1024;
#pragma unroll
    for (int i = 0; i < 4; ++i) sl[t + 256 * i] = lg[t + 256 * i];
    __syncthreads();
    for (int pass = 0; pass < KSEL; ++pass) {
        float bv = -INFINITY;
        int bi = 0;
#pragma unroll
        for (int i = 0; i < 4; ++i) {
            float v = sl[t + 256 * i];
            if (v > bv) { bv = v; bi = t + 256 * i; }
        }
        rv[t] = bv; ri[t] = bi;
        __syncthreads();
        for (int s = 128; s > 0; s >>= 1) {
            if (t < s) {
                if (rv[t + s] > rv[t]) { rv[t] = rv[t + s]; ri[t] = ri[t + s]; }
            }
            __syncthreads();
        }
        if (t == 0) { sth = rv[0]; sl[ri[0]] = -INFINITY; }
        __syncthreads();
    }
    float th = sth;
#pragma unroll
    for (int i = 0; i < 4; ++i) {
        float v = lg[t + 256 * i];
        out[(size_t)g * 1024 + t + 256 * i] = (v >= th) ? 1.f : 0.f;
    }
}

// =====================================================================================
extern "C" void kernel_launch(void* const* d_in, const int* in_sizes, int n_in,
                              void* d_out, int out_size, void* d_ws, size_t ws_size,
                              hipStream_t stream) {
    const float* x        = (const float*)d_in[0];
    const int*   edge_src = (const int*)d_in[1];
    const int*   edge_dst = (const int*)d_in[2];
    const float* W0 = (const float*)d_in[4];
    const float* b0 = (const float*)d_in[5];
    const float* W1 = (const float*)d_in[6];
    const float* b1 = (const float*)d_in[7];
    const float* Wf = (const float*)d_in[8];
    const float* bf = (const float*)d_in[9];
    const float* W2 = (const float*)d_in[10];
    const float* b2 = (const float*)d_in[11];
    const float* W3 = (const float*)d_in[12];
    const float* b3 = (const float*)d_in[13];
    float* out = (float*)d_out;

    char* w = (char*)d_ws;
    int*   cnt    = (int*)w;   w += (size_t)NTOT * 4;
    float* dinv   = (float*)w; w += (size_t)NTOT * 4;
    int*   col    = (int*)w;   w += (size_t)NTOT * MAXDEG * 4;
    int2*  iw     = (int2*)w;  w += (size_t)NTOT * MAXDEG * 8;
    float* P      = (float*)w; w += (size_t)NTOT * 128 * 4;
    float* Q      = (float*)w; w += (size_t)NTOT * 128 * 4;
    float* part   = (float*)w; w += (size_t)NB * 128 * 4;
    float* gproj  = (float*)w; w += (size_t)NB * 128 * 4;
    float* lin3p  = (float*)w; w += (size_t)NCH * NTOT * 4;
    float* lin3   = (float*)w; w += (size_t)NTOT * 4;
    float* logits = (float*)w; w += (size_t)NTOT * 4;

    hipMemsetAsync(cnt, 0, (size_t)NTOT * 4, stream);
    csr_k<<<ETOT / 256, 256, 0, stream>>>(edge_src, edge_dst, cnt, col);
    dinv_k<<<NTOT / 256, 256, 0, stream>>>(cnt, dinv);
    wgt_k<<<NTOT * MAXDEG / 256, 256, 0, stream>>>(col, cnt, dinv, iw);

    // conv0: P = relu(agg(x@W0)+b0) in-place; fused per-graph max -> part
    gemm_k<<<NTOT / 64, 256, 0, stream>>>(x, W0, P, nullptr, FEAT);
    agg_k<<<NB * NCH, 1024, 0, stream>>>(P, iw, cnt, dinv, b0, P, nullptr, nullptr, part);

    glob_k<<<NB, 128, 0, stream>>>(part, Wf, bf, W2, gproj);

    // conv1 twice (same weights), ping-pong P/Q, aggs in-place
    gemm_k<<<NTOT / 64, 256, 0, stream>>>(P, W1, Q, nullptr, HID);
    agg_k<<<NB * NCH, 1024, 0, stream>>>(Q, iw, cnt, dinv, b1, Q, nullptr, nullptr, nullptr);
    gemm_k<<<NTOT / 64, 256, 0, stream>>>(Q, W1, P, nullptr, HID);
    agg_k<<<NB * NCH, 1024, 0, stream>>>(P, iw, cnt, dinv, b1, P, nullptr, nullptr, nullptr);

    // conv2 on concat (gproj added in gemm epilogue, pre-agg); fused lin3 partials, no dense out
    gemm_k<<<NTOT / 64, 256, 0, stream>>>(P, W2, Q, gproj, HID);
    agg_k<<<NB * NCH, 1024, 0, stream>>>(Q, iw, cnt, dinv, b2, nullptr, lin3p, W3, nullptr);

    lin3sum_k<<<NTOT / 256, 256, 0, stream>>>(lin3p, lin3);
    sagg_k<<<NTOT / 256, 256, 0, stream>>>(lin3, iw, cnt, dinv, b3, logits);
    mask_k<<<NB, 256, 0, stream>>>(logits, out);
}